// Round 7
// baseline (238.160 us; speedup 1.0000x reference)
//
#include <hip/hip_runtime.h>
#include <math.h>

#define N_NODES 100000
#define N_EDGES 1600000
#define D 64
#define RPB 128                  // rows per bucket
#define NBUK 782                 // ceil(N_NODES/128)
#define CAP 3072                 // LDS edge buffer (bucket mean 2046, +22 sigma)
#define NGB 6250                 // gemm blocks
#define NHB 196                  // hist/place blocks
#define EPH 8192                 // edges per hist/place block (196*8192 >= 1.6M)

typedef unsigned int u32;
typedef unsigned short u16;

static __device__ __forceinline__ u16 f2bf(float x) {   // RNE fp32->bf16
    u32 u = __float_as_uint(x);
    u32 r = u + 0x7FFFu + ((u >> 16) & 1u);
    return (u16)(r >> 16);
}
static __device__ __forceinline__ float bflo(u32 u) { return __uint_as_float(u << 16); }
static __device__ __forceinline__ float bfhi(u32 u) { return __uint_as_float(u & 0xFFFF0000u); }
static __device__ __forceinline__ float selu(float x) {
    const float scale = 1.0507009873554805f;
    const float alpha = 1.6732632423543772f;
    return x > 0.f ? scale * x : scale * alpha * (expf(x) - 1.f);
}

// ---------------------------------------------------------------------------
// K1: fused. Blocks [0,6250): h_bf16 = bf16(feat @ kern).
//     Blocks [6250,6446): bucket histogram -> per-block private counts
//     (plain stores; no zeroing kernel, no global atomics).
// ---------------------------------------------------------------------------
__global__ __launch_bounds__(256) void fused_gemm_hist(
    const float* __restrict__ feat, const float* __restrict__ kern,
    const int* __restrict__ erow, u16* __restrict__ hbf,
    u32* __restrict__ pcnt)
{
    __shared__ u32 smem[5120];   // 20 KB, shared by both branches
    const int t = threadIdx.x;

    if (blockIdx.x < NGB) {
        float* ks = (float*)smem;            // 64x64 kernel tile
        float* fs = (float*)(smem + 4096);   // 16 feature rows
        const int row0 = blockIdx.x * 16;

        const float4* k4 = (const float4*)kern;
        float4* ks4 = (float4*)ks;
        #pragma unroll
        for (int i = 0; i < 4; i++) ks4[t + 256 * i] = k4[t + 256 * i];
        ((float4*)fs)[t] = ((const float4*)(feat + (size_t)row0 * D))[t];
        __syncthreads();

        const int r  = t >> 4;
        const int cg = t & 15;

        float4 acc = make_float4(0.f, 0.f, 0.f, 0.f);
        #pragma unroll
        for (int k4i = 0; k4i < 16; k4i++) {
            float4 f  = ((const float4*)(fs + r * D))[k4i];
            float4 k0 = ((const float4*)(ks + (4 * k4i + 0) * D))[cg];
            float4 k1 = ((const float4*)(ks + (4 * k4i + 1) * D))[cg];
            float4 k2 = ((const float4*)(ks + (4 * k4i + 2) * D))[cg];
            float4 k3 = ((const float4*)(ks + (4 * k4i + 3) * D))[cg];
            acc.x += f.x * k0.x + f.y * k1.x + f.z * k2.x + f.w * k3.x;
            acc.y += f.x * k0.y + f.y * k1.y + f.z * k2.y + f.w * k3.y;
            acc.z += f.x * k0.z + f.y * k1.z + f.z * k2.z + f.w * k3.z;
            acc.w += f.x * k0.w + f.y * k1.w + f.z * k2.w + f.w * k3.w;
        }
        ushort4 o;
        o.x = f2bf(acc.x); o.y = f2bf(acc.y);
        o.z = f2bf(acc.z); o.w = f2bf(acc.w);
        ((ushort4*)(hbf + (size_t)(row0 + r) * D))[cg] = o;
    } else {
        u32* c = smem;   // 782 counters
        for (int i = t; i < NBUK; i += 256) c[i] = 0u;
        __syncthreads();
        const int hb = blockIdx.x - NGB;
        const int base = hb * EPH;
        #pragma unroll
        for (int k = 0; k < 32; k++) {
            int i = base + k * 256 + t;
            if (i < N_EDGES) atomicAdd(&c[erow[i] >> 7], 1u);
        }
        __syncthreads();
        for (int i = t; i < NBUK; i += 256)
            pcnt[(size_t)hb * NBUK + i] = c[i];
    }
}

// ---------------------------------------------------------------------------
// K2: single block. bcnt = column-sum of pcnt; boff = exclusive scan
// (boff[NBUK] = total); pcnt rewritten in place to per-(block,bucket) BASE
// offsets so place needs no atomics and no count pass.
// ---------------------------------------------------------------------------
__global__ __launch_bounds__(1024) void scan_kernel(
    u32* __restrict__ pcnt, u32* __restrict__ boff)
{
    __shared__ u32 s[1024];
    const int t = threadIdx.x;

    u32 v = 0u;
    if (t < NBUK) {
        #pragma unroll 4
        for (int hb = 0; hb < NHB; hb++) v += pcnt[(size_t)hb * NBUK + t];
    }
    s[t] = v;
    __syncthreads();
    for (int d = 1; d < 1024; d <<= 1) {
        u32 a = (t >= d) ? s[t - d] : 0u;
        __syncthreads();
        s[t] += a;
        __syncthreads();
    }
    if (t < NBUK) {
        u32 e = s[t] - v;          // exclusive
        boff[t] = e;
        if (t == NBUK - 1) boff[NBUK] = s[t];
        u32 run = e;
        #pragma unroll 4
        for (int hb = 0; hb < NHB; hb++) {
            u32 cv = pcnt[(size_t)hb * NBUK + t];
            pcnt[(size_t)hb * NBUK + t] = run;
            run += cv;
        }
    }
}

// ---------------------------------------------------------------------------
// K3: place — single pass. Rank via native u32 LDS atomics; global position
// = precomputed per-(block,bucket) base + rank. Packs (col | rl<<17, val).
// ---------------------------------------------------------------------------
__global__ __launch_bounds__(1024) void place_kernel(
    const int* __restrict__ erow, const int* __restrict__ ecol,
    const float* __restrict__ eval, const u32* __restrict__ pbase,
    int2* __restrict__ sedge)
{
    __shared__ u32 c[NBUK];
    __shared__ u32 bl[NBUK];
    const int t = threadIdx.x;
    const int hb = blockIdx.x;
    for (int i = t; i < NBUK; i += 1024) {
        c[i] = 0u;
        bl[i] = pbase[(size_t)hb * NBUK + i];
    }
    __syncthreads();

    const int base = hb * EPH;
    #pragma unroll
    for (int k = 0; k < 8; k++) {
        int i = base + k * 1024 + t;
        if (i < N_EDGES) {
            int r = erow[i];
            int b = r >> 7;
            u32 rk = atomicAdd(&c[b], 1u);
            sedge[bl[b] + rk] = make_int2(ecol[i] | ((r & 127) << 17),
                                          __float_as_int(eval[i]));
        }
    }
}

// ---------------------------------------------------------------------------
// K4: aggregation. One block per 128-row bucket: in-LDS counting sort by
// local row, then wave-per-row gather on bf16 h: 8 lanes/edge, each lane
// loads uint4 (8 bf16 dims) -> one dwordx4 per 8 edges (1 KB/wave-instr).
// Shuffle reduce over sub-groups; fused skip/bias + SELU epilogue.
// ---------------------------------------------------------------------------
__global__ __launch_bounds__(1024) void agg_kernel(
    const u32* __restrict__ boff, const int2* __restrict__ sedge,
    const u16* __restrict__ hbf, const float* __restrict__ skip,
    const float* __restrict__ bias, float* __restrict__ out)
{
    __shared__ int2 ebuf[CAP];        // 24 KB row-sorted edges
    __shared__ u32 c[RPB];
    __shared__ u32 o[RPB];
    __shared__ u32 cur[RPB];

    const int t = threadIdx.x;
    const int w = t >> 6;
    const int lane = t & 63;
    const int b = blockIdx.x;

    const u32 beg = boff[b];
    const u32 cnt = boff[b + 1] - beg;

    if (t < RPB) c[t] = 0u;
    __syncthreads();

    for (u32 j = (u32)t; j < cnt; j += 1024u)
        atomicAdd(&c[(u32)sedge[beg + j].x >> 17], 1u);
    __syncthreads();

    if (t < RPB) o[t] = c[t];
    __syncthreads();
    for (int d = 1; d < RPB; d <<= 1) {
        u32 a = 0u;
        if (t < RPB && t >= d) a = o[t - d];
        __syncthreads();
        if (t < RPB && t >= d) o[t] += a;
        __syncthreads();
    }
    if (t < RPB) { u32 e = o[t] - c[t]; o[t] = e; cur[t] = e; }
    __syncthreads();

    for (u32 j = (u32)t; j < cnt; j += 1024u) {
        int2 e = sedge[beg + j];
        u32 rl = (u32)e.x >> 17;
        u32 rk = atomicAdd(&cur[rl], 1u);
        if (rk < CAP) ebuf[rk] = make_int2(e.x & 0x1FFFF, e.y);
    }
    __syncthreads();

    const int rows = min(RPB, N_NODES - b * RPB);
    const int sub = lane >> 3;   // 0..7: edge within group of 8
    const int dg  = lane & 7;    // 8 dims per lane

    for (int rl = w; rl < rows; rl += 16) {
        const u32 jb = o[rl];
        const u32 n  = c[rl];
        float a0 = 0.f, a1 = 0.f, a2 = 0.f, a3 = 0.f;
        float a4 = 0.f, a5 = 0.f, a6 = 0.f, a7 = 0.f;

        for (u32 j = 0; j < n; j += 16u) {
            u32 ja = j + (u32)sub;
            u32 jc = j + 8u + (u32)sub;
            int2 ea = (ja < n && jb + ja < CAP) ? ebuf[jb + ja] : make_int2(0, 0);
            int2 ec = (jc < n && jb + jc < CAP) ? ebuf[jb + jc] : make_int2(0, 0);
            float va = __int_as_float(ea.y);
            float vc = __int_as_float(ec.y);
            uint4 ha = ((const uint4*)(hbf + (size_t)ea.x * D))[dg];
            uint4 hc = ((const uint4*)(hbf + (size_t)ec.x * D))[dg];
            a0 += va * bflo(ha.x); a1 += va * bfhi(ha.x);
            a2 += va * bflo(ha.y); a3 += va * bfhi(ha.y);
            a4 += va * bflo(ha.z); a5 += va * bfhi(ha.z);
            a6 += va * bflo(ha.w); a7 += va * bfhi(ha.w);
            a0 += vc * bflo(hc.x); a1 += vc * bfhi(hc.x);
            a2 += vc * bflo(hc.y); a3 += vc * bfhi(hc.y);
            a4 += vc * bflo(hc.z); a5 += vc * bfhi(hc.z);
            a6 += vc * bflo(hc.w); a7 += vc * bfhi(hc.w);
        }

        #pragma unroll
        for (int m = 8; m <= 32; m <<= 1) {
            a0 += __shfl_xor(a0, m); a1 += __shfl_xor(a1, m);
            a2 += __shfl_xor(a2, m); a3 += __shfl_xor(a3, m);
            a4 += __shfl_xor(a4, m); a5 += __shfl_xor(a5, m);
            a6 += __shfl_xor(a6, m); a7 += __shfl_xor(a7, m);
        }

        if (sub == 0) {
            const int grow = b * RPB + rl;
            uint4 hr = ((const uint4*)(hbf + (size_t)grow * D))[dg];
            float4 s0 = ((const float4*)skip)[2 * dg];
            float4 s1 = ((const float4*)skip)[2 * dg + 1];
            float4 b0 = ((const float4*)bias)[2 * dg];
            float4 b1 = ((const float4*)bias)[2 * dg + 1];
            float4 x0, x1;
            x0.x = selu(bflo(hr.x) * s0.x + b0.x + a0);
            x0.y = selu(bfhi(hr.x) * s0.y + b0.y + a1);
            x0.z = selu(bflo(hr.y) * s0.z + b0.z + a2);
            x0.w = selu(bfhi(hr.y) * s0.w + b0.w + a3);
            x1.x = selu(bflo(hr.z) * s1.x + b1.x + a4);
            x1.y = selu(bfhi(hr.z) * s1.y + b1.y + a5);
            x1.z = selu(bflo(hr.w) * s1.z + b1.z + a6);
            x1.w = selu(bfhi(hr.w) * s1.w + b1.w + a7);
            ((float4*)(out + (size_t)grow * D))[2 * dg]     = x0;
            ((float4*)(out + (size_t)grow * D))[2 * dg + 1] = x1;
        }
    }
}

extern "C" void kernel_launch(void* const* d_in, const int* in_sizes, int n_in,
                              void* d_out, int out_size, void* d_ws, size_t ws_size,
                              hipStream_t stream)
{
    const float* feat = (const float*)d_in[0];
    const float* kern = (const float*)d_in[1];
    const float* bias = (const float*)d_in[2];
    const float* skip = (const float*)d_in[3];
    const int*   erow = (const int*)d_in[4];
    const int*   ecol = (const int*)d_in[5];
    const float* eval = (const float*)d_in[6];
    float* out = (float*)d_out;

    // workspace layout (16B-aligned segments)
    u16*  hbf   = (u16*)d_ws;                            // 6,400,000 u16 (12.8 MB)
    u32*  pcnt  = (u32*)(hbf + (size_t)N_NODES * D);     // 196*782 (613 KB)
    u32*  boff  = pcnt + (size_t)NHB * NBUK + 14;        // NBUK+1 (pad to 16B: 196*782+14 ≡ 0 mod 4)
    int2* sedge = (int2*)(boff + 1024);                  // 1,600,000 int2 (12.8 MB)
    // total ~26.3 MB

    hipLaunchKernelGGL(fused_gemm_hist, dim3(NGB + NHB), dim3(256), 0, stream,
                       feat, kern, erow, hbf, pcnt);
    hipLaunchKernelGGL(scan_kernel, dim3(1), dim3(1024), 0, stream,
                       pcnt, boff);
    hipLaunchKernelGGL(place_kernel, dim3(NHB), dim3(1024), 0, stream,
                       erow, ecol, eval, pcnt, sedge);
    hipLaunchKernelGGL(agg_kernel, dim3(NBUK), dim3(1024), 0, stream,
                       boff, sedge, hbf, skip, bias, out);
}

// Round 8
// 224.440 us; speedup vs baseline: 1.0611x; 1.0611x over previous
//
#include <hip/hip_runtime.h>
#include <math.h>

#define N_NODES 100000
#define N_EDGES 1600000
#define D 64
#define RPB 128                  // rows per bucket
#define NBUK 782                 // ceil(N_NODES/128)
#define CAP 3072                 // LDS edge buffer (bucket mean 2048, +22 sigma)
#define NGB 782                  // gemm blocks (128 rows each)
#define NHB 196                  // hist/place blocks
#define EPH 8192                 // edges per hist/place block

typedef unsigned int u32;
typedef unsigned short u16;

static __device__ __forceinline__ u32 f2bf(float x) {   // RNE fp32->bf16 (low 16)
    u32 u = __float_as_uint(x);
    u32 r = u + 0x7FFFu + ((u >> 16) & 1u);
    return r >> 16;
}
static __device__ __forceinline__ u32 pack2(float a, float b) {
    return f2bf(a) | (f2bf(b) << 16);
}
static __device__ __forceinline__ float bflo(u32 u) { return __uint_as_float(u << 16); }
static __device__ __forceinline__ float bfhi(u32 u) { return __uint_as_float(u & 0xFFFF0000u); }
static __device__ __forceinline__ float selu(float x) {
    const float scale = 1.0507009873554805f;
    const float alpha = 1.6732632423543772f;
    return x > 0.f ? scale * x : scale * alpha * (expf(x) - 1.f);
}

// ---------------------------------------------------------------------------
// K1 fused. Blocks [0,782): bf16 h = feat @ kern, register-tiled 4r x 8c per
// thread; kern in LDS, feat streamed direct from global (VMEM pipe).
// Blocks [782,978): bucket histogram -> per-block private counts (plain
// stores, no zeroing dependency).
// ---------------------------------------------------------------------------
__global__ __launch_bounds__(256) void fused_gemm_hist(
    const float* __restrict__ feat, const float* __restrict__ kern,
    const int* __restrict__ erow, u16* __restrict__ hbf,
    u32* __restrict__ pcnt)
{
    __shared__ u32 smem[4096];   // 16 KB: kern tile OR hist counters
    const int t = threadIdx.x;

    if (blockIdx.x < NGB) {
        float* ks = (float*)smem;   // 64x64 kernel, row-major [k][c]
        {
            const float4* k4 = (const float4*)kern;
            float4* ks4 = (float4*)ks;
            #pragma unroll
            for (int i = 0; i < 4; i++) ks4[t + 256 * i] = k4[t + 256 * i];
        }
        __syncthreads();

        const int cgi  = t & 7;                      // 8 col-groups (8 cols)
        const int rg   = t >> 3;                     // 32 row-groups (4 rows)
        const int row0 = blockIdx.x * RPB + rg * 4;

        float4 acc[4][2];
        #pragma unroll
        for (int r = 0; r < 4; r++)
            #pragma unroll
            for (int i = 0; i < 2; i++)
                acc[r][i] = make_float4(0.f, 0.f, 0.f, 0.f);

        #pragma unroll 4
        for (int s = 0; s < 16; s++) {               // k4-step: 4 k-values
            float4 f[4];
            #pragma unroll
            for (int r = 0; r < 4; r++) {
                int row = min(row0 + r, N_NODES - 1);
                f[r] = ((const float4*)(feat + (size_t)row * D))[s];
            }
            float4 kk[4][2];
            #pragma unroll
            for (int kv = 0; kv < 4; kv++)
                #pragma unroll
                for (int i = 0; i < 2; i++)
                    kk[kv][i] = ((const float4*)(ks + (s * 4 + kv) * D))[cgi * 2 + i];
            #pragma unroll
            for (int r = 0; r < 4; r++) {
                #pragma unroll
                for (int kv = 0; kv < 4; kv++) {
                    float fv = (&f[r].x)[kv];
                    #pragma unroll
                    for (int i = 0; i < 2; i++) {
                        acc[r][i].x += fv * kk[kv][i].x;
                        acc[r][i].y += fv * kk[kv][i].y;
                        acc[r][i].z += fv * kk[kv][i].z;
                        acc[r][i].w += fv * kk[kv][i].w;
                    }
                }
            }
        }

        #pragma unroll
        for (int r = 0; r < 4; r++) {
            int row = row0 + r;
            if (row < N_NODES) {
                uint4 o;
                o.x = pack2(acc[r][0].x, acc[r][0].y);
                o.y = pack2(acc[r][0].z, acc[r][0].w);
                o.z = pack2(acc[r][1].x, acc[r][1].y);
                o.w = pack2(acc[r][1].z, acc[r][1].w);
                ((uint4*)(hbf + (size_t)row * D))[cgi] = o;
            }
        }
    } else {
        u32* c = smem;   // 782 counters
        for (int i = t; i < NBUK; i += 256) c[i] = 0u;
        __syncthreads();
        const int hb = blockIdx.x - NGB;
        const int base = hb * EPH;
        #pragma unroll
        for (int k = 0; k < 32; k++) {
            int i = base + k * 256 + t;
            if (i < N_EDGES) atomicAdd(&c[erow[i] >> 7], 1u);
        }
        __syncthreads();
        for (int i = t; i < NBUK; i += 256)
            pcnt[(size_t)hb * NBUK + i] = c[i];
    }
}

// ---------------------------------------------------------------------------
// K2: single block. Column-sum of pcnt (independent loads, pipelined),
// exclusive scan -> boff (boff[NBUK] = total), cur = boff.
// ---------------------------------------------------------------------------
__global__ __launch_bounds__(1024) void scan_kernel(
    const u32* __restrict__ pcnt, u32* __restrict__ boff, u32* __restrict__ cur)
{
    __shared__ u32 s[1024];
    const int t = threadIdx.x;

    u32 v = 0u;
    if (t < NBUK) {
        #pragma unroll 4
        for (int hb = 0; hb < NHB; hb++) v += pcnt[(size_t)hb * NBUK + t];
    }
    s[t] = v;
    __syncthreads();
    for (int d = 1; d < 1024; d <<= 1) {
        u32 a = (t >= d) ? s[t - d] : 0u;
        __syncthreads();
        s[t] += a;
        __syncthreads();
    }
    if (t < NBUK) {
        u32 e = s[t] - v;
        boff[t] = e;
        cur[t] = e;
        if (t == NBUK - 1) boff[NBUK] = s[t];
    }
}

// ---------------------------------------------------------------------------
// K3: place. Per block: LDS count -> reserve contiguous range per bucket
// (one global atomic per bucket per block) -> LDS rank -> dense 8B stores.
// Packs (col | row_local<<17, val).
// ---------------------------------------------------------------------------
__global__ __launch_bounds__(1024) void place_kernel(
    const int* __restrict__ erow, const int* __restrict__ ecol,
    const float* __restrict__ eval, u32* __restrict__ cur,
    int2* __restrict__ sedge)
{
    __shared__ u32 c[NBUK];
    __shared__ u32 bl[NBUK];
    const int t = threadIdx.x;
    for (int i = t; i < NBUK; i += 1024) c[i] = 0u;
    __syncthreads();

    const int base = blockIdx.x * EPH;
    #pragma unroll
    for (int k = 0; k < 8; k++) {
        int i = base + k * 1024 + t;
        if (i < N_EDGES) atomicAdd(&c[erow[i] >> 7], 1u);
    }
    __syncthreads();
    for (int i = t; i < NBUK; i += 1024)
        bl[i] = c[i] ? atomicAdd(&cur[i], c[i]) : 0u;
    __syncthreads();
    for (int i = t; i < NBUK; i += 1024) c[i] = 0u;
    __syncthreads();

    #pragma unroll
    for (int k = 0; k < 8; k++) {
        int i = base + k * 1024 + t;
        if (i < N_EDGES) {
            int r = erow[i];
            int b = r >> 7;
            u32 rk = atomicAdd(&c[b], 1u);
            sedge[bl[b] + rk] = make_int2(ecol[i] | ((r & 127) << 17),
                                          __float_as_int(eval[i]));
        }
    }
}

// ---------------------------------------------------------------------------
// K4: aggregation (unchanged from R7). One block per 128-row bucket: in-LDS
// counting sort by local row, then wave-per-row bf16 gather (8 lanes/edge,
// uint4 = 8 dims/lane), shuffle reduce, fused skip/bias + SELU.
// ---------------------------------------------------------------------------
__global__ __launch_bounds__(1024) void agg_kernel(
    const u32* __restrict__ boff, const int2* __restrict__ sedge,
    const u16* __restrict__ hbf, const float* __restrict__ skip,
    const float* __restrict__ bias, float* __restrict__ out)
{
    __shared__ int2 ebuf[CAP];        // 24 KB row-sorted edges
    __shared__ u32 c[RPB];
    __shared__ u32 o[RPB];
    __shared__ u32 cur[RPB];

    const int t = threadIdx.x;
    const int w = t >> 6;
    const int lane = t & 63;
    const int b = blockIdx.x;

    const u32 beg = boff[b];
    const u32 cnt = boff[b + 1] - beg;

    if (t < RPB) c[t] = 0u;
    __syncthreads();

    for (u32 j = (u32)t; j < cnt; j += 1024u)
        atomicAdd(&c[(u32)sedge[beg + j].x >> 17], 1u);
    __syncthreads();

    if (t < RPB) o[t] = c[t];
    __syncthreads();
    for (int d = 1; d < RPB; d <<= 1) {
        u32 a = 0u;
        if (t < RPB && t >= d) a = o[t - d];
        __syncthreads();
        if (t < RPB && t >= d) o[t] += a;
        __syncthreads();
    }
    if (t < RPB) { u32 e = o[t] - c[t]; o[t] = e; cur[t] = e; }
    __syncthreads();

    for (u32 j = (u32)t; j < cnt; j += 1024u) {
        int2 e = sedge[beg + j];
        u32 rl = (u32)e.x >> 17;
        u32 rk = atomicAdd(&cur[rl], 1u);
        if (rk < CAP) ebuf[rk] = make_int2(e.x & 0x1FFFF, e.y);
    }
    __syncthreads();

    const int rows = min(RPB, N_NODES - b * RPB);
    const int sub = lane >> 3;   // 0..7: edge within group of 8
    const int dg  = lane & 7;    // 8 dims per lane

    for (int rl = w; rl < rows; rl += 16) {
        const u32 jb = o[rl];
        const u32 n  = c[rl];
        float a0 = 0.f, a1 = 0.f, a2 = 0.f, a3 = 0.f;
        float a4 = 0.f, a5 = 0.f, a6 = 0.f, a7 = 0.f;

        for (u32 j = 0; j < n; j += 16u) {
            u32 ja = j + (u32)sub;
            u32 jc = j + 8u + (u32)sub;
            int2 ea = (ja < n && jb + ja < CAP) ? ebuf[jb + ja] : make_int2(0, 0);
            int2 ec = (jc < n && jb + jc < CAP) ? ebuf[jb + jc] : make_int2(0, 0);
            float va = __int_as_float(ea.y);
            float vc = __int_as_float(ec.y);
            uint4 ha = ((const uint4*)(hbf + (size_t)ea.x * D))[dg];
            uint4 hc = ((const uint4*)(hbf + (size_t)ec.x * D))[dg];
            a0 += va * bflo(ha.x); a1 += va * bfhi(ha.x);
            a2 += va * bflo(ha.y); a3 += va * bfhi(ha.y);
            a4 += va * bflo(ha.z); a5 += va * bfhi(ha.z);
            a6 += va * bflo(ha.w); a7 += va * bfhi(ha.w);
            a0 += vc * bflo(hc.x); a1 += vc * bfhi(hc.x);
            a2 += vc * bflo(hc.y); a3 += vc * bfhi(hc.y);
            a4 += vc * bflo(hc.z); a5 += vc * bfhi(hc.z);
            a6 += vc * bflo(hc.w); a7 += vc * bfhi(hc.w);
        }

        #pragma unroll
        for (int m = 8; m <= 32; m <<= 1) {
            a0 += __shfl_xor(a0, m); a1 += __shfl_xor(a1, m);
            a2 += __shfl_xor(a2, m); a3 += __shfl_xor(a3, m);
            a4 += __shfl_xor(a4, m); a5 += __shfl_xor(a5, m);
            a6 += __shfl_xor(a6, m); a7 += __shfl_xor(a7, m);
        }

        if (sub == 0) {
            const int grow = b * RPB + rl;
            uint4 hr = ((const uint4*)(hbf + (size_t)grow * D))[dg];
            float4 s0 = ((const float4*)skip)[2 * dg];
            float4 s1 = ((const float4*)skip)[2 * dg + 1];
            float4 b0 = ((const float4*)bias)[2 * dg];
            float4 b1 = ((const float4*)bias)[2 * dg + 1];
            float4 x0, x1;
            x0.x = selu(bflo(hr.x) * s0.x + b0.x + a0);
            x0.y = selu(bfhi(hr.x) * s0.y + b0.y + a1);
            x0.z = selu(bflo(hr.y) * s0.z + b0.z + a2);
            x0.w = selu(bfhi(hr.y) * s0.w + b0.w + a3);
            x1.x = selu(bflo(hr.z) * s1.x + b1.x + a4);
            x1.y = selu(bfhi(hr.z) * s1.y + b1.y + a5);
            x1.z = selu(bflo(hr.w) * s1.z + b1.z + a6);
            x1.w = selu(bfhi(hr.w) * s1.w + b1.w + a7);
            ((float4*)(out + (size_t)grow * D))[2 * dg]     = x0;
            ((float4*)(out + (size_t)grow * D))[2 * dg + 1] = x1;
        }
    }
}

extern "C" void kernel_launch(void* const* d_in, const int* in_sizes, int n_in,
                              void* d_out, int out_size, void* d_ws, size_t ws_size,
                              hipStream_t stream)
{
    const float* feat = (const float*)d_in[0];
    const float* kern = (const float*)d_in[1];
    const float* bias = (const float*)d_in[2];
    const float* skip = (const float*)d_in[3];
    const int*   erow = (const int*)d_in[4];
    const int*   ecol = (const int*)d_in[5];
    const float* eval = (const float*)d_in[6];
    float* out = (float*)d_out;

    // workspace layout (all segments 16B-aligned)
    u16*  hbf   = (u16*)d_ws;                            // 6,400,000 u16 (12.8 MB)
    u32*  pcnt  = (u32*)(hbf + (size_t)N_NODES * D);     // 196*782 = 153,272 u32
    u32*  boff  = pcnt + (size_t)NHB * NBUK;             // 1024 u32 (783 used)
    u32*  cur   = boff + 1024;                           // 1024 u32
    int2* sedge = (int2*)(cur + 1024);                   // 1,600,000 int2 (12.8 MB)
    // total ~26.3 MB

    hipLaunchKernelGGL(fused_gemm_hist, dim3(NGB + NHB), dim3(256), 0, stream,
                       feat, kern, erow, hbf, pcnt);
    hipLaunchKernelGGL(scan_kernel, dim3(1), dim3(1024), 0, stream,
                       pcnt, boff, cur);
    hipLaunchKernelGGL(place_kernel, dim3(NHB), dim3(1024), 0, stream,
                       erow, ecol, eval, cur, sedge);
    hipLaunchKernelGGL(agg_kernel, dim3(NBUK), dim3(1024), 0, stream,
                       boff, sedge, hbf, skip, bias, out);
}

// Round 9
// 205.750 us; speedup vs baseline: 1.1575x; 1.0908x over previous
//
#include <hip/hip_runtime.h>
#include <math.h>

#define N_NODES 100000
#define N_EDGES 1600000
#define D 64
#define RPB 128                  // rows per bucket
#define NBUK 782                 // ceil(N_NODES/128)
#define CAP 3072                 // LDS edge buffer (bucket mean 2048, +22 sigma)
#define NGB 782                  // gemm blocks (128 rows each)
#define NHB 196                  // sort blocks
#define EPB 8192                 // edges per sort block (196*8192 >= 1.6M)
#define POFF_STRIDE 200          // padded row stride of poff[b][hb]

typedef unsigned int u32;
typedef unsigned short u16;

static __device__ __forceinline__ u32 f2bf(float x) {   // RNE fp32->bf16 (low 16)
    u32 u = __float_as_uint(x);
    u32 r = u + 0x7FFFu + ((u >> 16) & 1u);
    return r >> 16;
}
static __device__ __forceinline__ u32 pack2(float a, float b) {
    return f2bf(a) | (f2bf(b) << 16);
}
static __device__ __forceinline__ float bflo(u32 u) { return __uint_as_float(u << 16); }
static __device__ __forceinline__ float bfhi(u32 u) { return __uint_as_float(u & 0xFFFF0000u); }
static __device__ __forceinline__ float selu(float x) {
    const float scale = 1.0507009873554805f;
    const float alpha = 1.6732632423543772f;
    return x > 0.f ? scale * x : scale * alpha * (expf(x) - 1.f);
}

// ---------------------------------------------------------------------------
// K1 fused. Blocks [0,782): bf16 h = feat @ kern (register-tiled 4r x 8c,
// kern in LDS, feat streamed from global). Blocks [782,978): in-LDS counting
// sort of 8192 edges by bucket -> private contiguous sedge region + 783
// bucket offsets. erow staged in LDS (read once); no global atomics.
// ---------------------------------------------------------------------------
__global__ __launch_bounds__(256) void fused_gemm_sort(
    const float* __restrict__ feat, const float* __restrict__ kern,
    const int* __restrict__ erow, const int* __restrict__ ecol,
    const float* __restrict__ eval, u16* __restrict__ hbf,
    int2* __restrict__ sedge, u32* __restrict__ poff)
{
    __shared__ u32 smem[10795];  // 43.2 KB: gemm uses 16 KB; sort uses all
    const int t = threadIdx.x;

    if (blockIdx.x < NGB) {
        float* ks = (float*)smem;   // 64x64 kernel, row-major [k][c]
        {
            const float4* k4 = (const float4*)kern;
            float4* ks4 = (float4*)ks;
            #pragma unroll
            for (int i = 0; i < 4; i++) ks4[t + 256 * i] = k4[t + 256 * i];
        }
        __syncthreads();

        const int cgi  = t & 7;                      // 8 col-groups (8 cols)
        const int rg   = t >> 3;                     // 32 row-groups (4 rows)
        const int row0 = blockIdx.x * RPB + rg * 4;

        float4 acc[4][2];
        #pragma unroll
        for (int r = 0; r < 4; r++)
            #pragma unroll
            for (int i = 0; i < 2; i++)
                acc[r][i] = make_float4(0.f, 0.f, 0.f, 0.f);

        #pragma unroll 4
        for (int s = 0; s < 16; s++) {               // k4-step: 4 k-values
            float4 f[4];
            #pragma unroll
            for (int r = 0; r < 4; r++) {
                int row = min(row0 + r, N_NODES - 1);
                f[r] = ((const float4*)(feat + (size_t)row * D))[s];
            }
            float4 kk[4][2];
            #pragma unroll
            for (int kv = 0; kv < 4; kv++)
                #pragma unroll
                for (int i = 0; i < 2; i++)
                    kk[kv][i] = ((const float4*)(ks + (s * 4 + kv) * D))[cgi * 2 + i];
            #pragma unroll
            for (int r = 0; r < 4; r++) {
                #pragma unroll
                for (int kv = 0; kv < 4; kv++) {
                    float fv = (&f[r].x)[kv];
                    #pragma unroll
                    for (int i = 0; i < 2; i++) {
                        acc[r][i].x += fv * kk[kv][i].x;
                        acc[r][i].y += fv * kk[kv][i].y;
                        acc[r][i].z += fv * kk[kv][i].z;
                        acc[r][i].w += fv * kk[kv][i].w;
                    }
                }
            }
        }

        #pragma unroll
        for (int r = 0; r < 4; r++) {
            int row = row0 + r;
            if (row < N_NODES) {
                uint4 o;
                o.x = pack2(acc[r][0].x, acc[r][0].y);
                o.y = pack2(acc[r][0].z, acc[r][0].w);
                o.z = pack2(acc[r][1].x, acc[r][1].y);
                o.w = pack2(acc[r][1].z, acc[r][1].w);
                ((uint4*)(hbf + (size_t)row * D))[cgi] = o;
            }
        }
    } else {
        u32* er   = smem;                 // 8192: staged erow
        u32* c    = smem + 8192;          // 782 counts
        u32* o    = c + NBUK;             // 783 offsets
        u32* cu   = o + NBUK + 1;         // 782 cursors
        u32* part = cu + NBUK;            // 256 scan partials

        for (int i = t; i < NBUK; i += 256) c[i] = 0u;
        __syncthreads();

        const int hb   = blockIdx.x - NGB;
        const int base = hb * EPB;

        // pass 1: stage erow in LDS + bucket count (native u32 LDS atomics)
        #pragma unroll
        for (int k = 0; k < 32; k++) {
            int i = base + k * 256 + t;
            u32 r = 0xFFFFFFFFu;
            if (i < N_EDGES) { r = (u32)erow[i]; atomicAdd(&c[r >> 7], 1u); }
            er[k * 256 + t] = r;
        }
        __syncthreads();

        // blocked exclusive scan over 782 counts (4 per thread + 256-wide HS)
        const int i0 = t * 4;
        {
            u32 p = 0u;
            #pragma unroll
            for (int j = 0; j < 4; j++) { int i = i0 + j; if (i < NBUK) p += c[i]; }
            part[t] = p;
        }
        __syncthreads();
        for (int d = 1; d < 256; d <<= 1) {
            u32 a = (t >= d) ? part[t - d] : 0u;
            __syncthreads();
            part[t] += a;
            __syncthreads();
        }
        {
            u32 run = (t > 0) ? part[t - 1] : 0u;
            #pragma unroll
            for (int j = 0; j < 4; j++) {
                int i = i0 + j;
                if (i < NBUK) { o[i] = run; cu[i] = run; run += c[i]; }
            }
            if (t == 255) o[NBUK] = part[255];   // total edges in this block
        }
        __syncthreads();

        // pass 2: scatter into private contiguous region (L2-resident 64 KB)
        #pragma unroll
        for (int k = 0; k < 32; k++) {
            int i = base + k * 256 + t;
            if (i < N_EDGES) {
                u32 r = er[k * 256 + t];
                u32 rk = atomicAdd(&cu[r >> 7], 1u);
                sedge[(size_t)hb * EPB + rk] =
                    make_int2(ecol[i] | (int)((r & 127u) << 17),
                              __float_as_int(eval[i]));
            }
        }

        // publish 783 offsets, transposed for coalesced agg reads
        for (int i = t; i <= NBUK; i += 256)
            poff[(size_t)i * POFF_STRIDE + hb] = o[i];
    }
}

// ---------------------------------------------------------------------------
// K2: aggregation. One block per 128-row bucket. Phase A: append this
// bucket's 196 short runs into LDS (wave per run). Phase B: LDS->LDS
// counting sort by local row. Phase C: wave-per-row bf16 gather
// (8 lanes/edge, uint4 = 8 dims/lane), shuffle reduce, skip/bias + SELU.
// ---------------------------------------------------------------------------
__global__ __launch_bounds__(1024) void agg_kernel(
    const u32* __restrict__ poff, const int2* __restrict__ sedge,
    const u16* __restrict__ hbf, const float* __restrict__ skip,
    const float* __restrict__ bias, float* __restrict__ out)
{
    __shared__ int2 eA[CAP];          // 24 KB unsorted
    __shared__ int2 eB[CAP];          // 24 KB row-sorted
    __shared__ u32 c[RPB];
    __shared__ u32 o[RPB];
    __shared__ u32 cur[RPB];
    __shared__ u32 gcur;

    const int t = threadIdx.x;
    const int w = t >> 6;
    const int lane = t & 63;
    const int b = blockIdx.x;

    if (t == 0) gcur = 0u;
    if (t < RPB) c[t] = 0u;
    __syncthreads();

    // phase A: pull 196 runs into eA (run lengths are wave-uniform)
    for (int hb = w; hb < NHB; hb += 16) {
        u32 s0 = poff[(size_t)b * POFF_STRIDE + hb];
        u32 s1 = poff[(size_t)(b + 1) * POFF_STRIDE + hb];
        u32 len = s1 - s0;
        if (len) {
            u32 base = 0u;
            if (lane == 0) base = atomicAdd(&gcur, len);
            base = __shfl(base, 0);
            for (u32 j = (u32)lane; j < len; j += 64u) {
                if (base + j < CAP)
                    eA[base + j] = sedge[(size_t)hb * EPB + s0 + j];
            }
        }
    }
    __syncthreads();
    const u32 cnt = min(gcur, (u32)CAP);

    // phase B: count by local row
    for (u32 j = (u32)t; j < cnt; j += 1024u)
        atomicAdd(&c[(u32)eA[j].x >> 17], 1u);
    __syncthreads();

    if (t < RPB) o[t] = c[t];
    __syncthreads();
    for (int d = 1; d < RPB; d <<= 1) {
        u32 a = 0u;
        if (t < RPB && t >= d) a = o[t - d];
        __syncthreads();
        if (t < RPB && t >= d) o[t] += a;
        __syncthreads();
    }
    if (t < RPB) { u32 e = o[t] - c[t]; o[t] = e; cur[t] = e; }
    __syncthreads();

    for (u32 j = (u32)t; j < cnt; j += 1024u) {
        int2 e = eA[j];
        u32 rl = (u32)e.x >> 17;
        u32 rk = atomicAdd(&cur[rl], 1u);
        if (rk < CAP) eB[rk] = make_int2(e.x & 0x1FFFF, e.y);
    }
    __syncthreads();

    // phase C: per-row gather + reduce
    const int rows = min(RPB, N_NODES - b * RPB);
    const int sub = lane >> 3;   // 0..7: edge within group of 8
    const int dg  = lane & 7;    // 8 dims per lane

    for (int rl = w; rl < rows; rl += 16) {
        const u32 jb = o[rl];
        const u32 n  = c[rl];
        float a0 = 0.f, a1 = 0.f, a2 = 0.f, a3 = 0.f;
        float a4 = 0.f, a5 = 0.f, a6 = 0.f, a7 = 0.f;

        for (u32 j = 0; j < n; j += 16u) {
            u32 ja = j + (u32)sub;
            u32 jc = j + 8u + (u32)sub;
            int2 ea = (ja < n && jb + ja < CAP) ? eB[jb + ja] : make_int2(0, 0);
            int2 ec = (jc < n && jb + jc < CAP) ? eB[jb + jc] : make_int2(0, 0);
            float va = __int_as_float(ea.y);
            float vc = __int_as_float(ec.y);
            uint4 ha = ((const uint4*)(hbf + (size_t)ea.x * D))[dg];
            uint4 hc = ((const uint4*)(hbf + (size_t)ec.x * D))[dg];
            a0 += va * bflo(ha.x); a1 += va * bfhi(ha.x);
            a2 += va * bflo(ha.y); a3 += va * bfhi(ha.y);
            a4 += va * bflo(ha.z); a5 += va * bfhi(ha.z);
            a6 += va * bflo(ha.w); a7 += va * bfhi(ha.w);
            a0 += vc * bflo(hc.x); a1 += vc * bfhi(hc.x);
            a2 += vc * bflo(hc.y); a3 += vc * bfhi(hc.y);
            a4 += vc * bflo(hc.z); a5 += vc * bfhi(hc.z);
            a6 += vc * bflo(hc.w); a7 += vc * bfhi(hc.w);
        }

        #pragma unroll
        for (int m = 8; m <= 32; m <<= 1) {
            a0 += __shfl_xor(a0, m); a1 += __shfl_xor(a1, m);
            a2 += __shfl_xor(a2, m); a3 += __shfl_xor(a3, m);
            a4 += __shfl_xor(a4, m); a5 += __shfl_xor(a5, m);
            a6 += __shfl_xor(a6, m); a7 += __shfl_xor(a7, m);
        }

        if (sub == 0) {
            const int grow = b * RPB + rl;
            uint4 hr = ((const uint4*)(hbf + (size_t)grow * D))[dg];
            float4 s0 = ((const float4*)skip)[2 * dg];
            float4 s1 = ((const float4*)skip)[2 * dg + 1];
            float4 b0 = ((const float4*)bias)[2 * dg];
            float4 b1 = ((const float4*)bias)[2 * dg + 1];
            float4 x0, x1;
            x0.x = selu(bflo(hr.x) * s0.x + b0.x + a0);
            x0.y = selu(bfhi(hr.x) * s0.y + b0.y + a1);
            x0.z = selu(bflo(hr.y) * s0.z + b0.z + a2);
            x0.w = selu(bfhi(hr.y) * s0.w + b0.w + a3);
            x1.x = selu(bflo(hr.z) * s1.x + b1.x + a4);
            x1.y = selu(bfhi(hr.z) * s1.y + b1.y + a5);
            x1.z = selu(bflo(hr.w) * s1.z + b1.z + a6);
            x1.w = selu(bfhi(hr.w) * s1.w + b1.w + a7);
            ((float4*)(out + (size_t)grow * D))[2 * dg]     = x0;
            ((float4*)(out + (size_t)grow * D))[2 * dg + 1] = x1;
        }
    }
}

extern "C" void kernel_launch(void* const* d_in, const int* in_sizes, int n_in,
                              void* d_out, int out_size, void* d_ws, size_t ws_size,
                              hipStream_t stream)
{
    const float* feat = (const float*)d_in[0];
    const float* kern = (const float*)d_in[1];
    const float* bias = (const float*)d_in[2];
    const float* skip = (const float*)d_in[3];
    const int*   erow = (const int*)d_in[4];
    const int*   ecol = (const int*)d_in[5];
    const float* eval = (const float*)d_in[6];
    float* out = (float*)d_out;

    // workspace layout (all segments 16B-aligned)
    u16*  hbf   = (u16*)d_ws;                            // 6,400,000 u16 (12.8 MB)
    u32*  poff  = (u32*)(hbf + (size_t)N_NODES * D);     // 783*200 = 156,600 u32
    int2* sedge = (int2*)(poff + 156600);                // 196*8192 int2 (12.85 MB)
    // total ~26.3 MB

    hipLaunchKernelGGL(fused_gemm_sort, dim3(NGB + NHB), dim3(256), 0, stream,
                       feat, kern, erow, ecol, eval, hbf, sedge, poff);
    hipLaunchKernelGGL(agg_kernel, dim3(NBUK), dim3(1024), 0, stream,
                       poff, sedge, hbf, skip, bias, out);
}